// Round 1
// baseline (4287.179 us; speedup 1.0000x reference)
//
#include <hip/hip_runtime.h>

// K-means assignment: argmin_k ||x_n - c_k||  via  x2 + c2 - 2*x.cT, fused argmin.
// N=131072, K=2048, D=512, fp32 inputs, int32 output.
//
// Compute-bound on fp32 VALU (no fp32 MFMA on CDNA4): floor = 2*N*K*D/157.3TF ~ 1.75ms.

#define N_PTS 131072
#define K_CL  2048
#define D_DIM 512

#define BM 128
#define BN 128
#define BK 32

// One wave per row: sum of squares of a 512-float row.
__global__ void row_norms_kernel(const float* __restrict__ A,
                                 float* __restrict__ out, int rows) {
    int gid  = blockIdx.x * blockDim.x + threadIdx.x;
    int wave = gid >> 6;
    int lane = gid & 63;
    if (wave >= rows) return;
    const float4* a = (const float4*)(A + (size_t)wave * D_DIM);
    float4 p = a[lane];        // d = lane*4        (coalesced 1KB/wave)
    float4 q = a[lane + 64];   // d = 256 + lane*4
    float s = p.x*p.x + p.y*p.y + p.z*p.z + p.w*p.w
            + q.x*q.x + q.y*q.y + q.z*q.z + q.w*q.w;
    #pragma unroll
    for (int off = 32; off > 0; off >>= 1) s += __shfl_down(s, off, 64);
    if (lane == 0) out[wave] = s;
}

// Block owns 128 rows, loops over all 2048 clusters in 128-col tiles,
// 8x8 acc per thread. LDS tiles are d-major with a (row + 4d)&127 rotation
// swizzle: conflict-free compute reads (b128), 4-way-max staging writes.
__global__ __launch_bounds__(256, 3)
void kmeans_argmin_kernel(const float* __restrict__ X,
                          const float* __restrict__ C,
                          const float* __restrict__ x2,   // [N] (may be null)
                          const float* __restrict__ c2,   // [K]
                          int* __restrict__ out) {
    __shared__ __align__(16) float smem[BK * BM + BK * BN];   // 32 KB
    float* Xs = smem;
    float* Cs = smem + BK * BM;

    const int tid = threadIdx.x;
    const int tx  = tid & 15;   // 16 col-groups
    const int ty  = tid >> 4;   // 16 row-groups
    const int rowBase = blockIdx.x * BM;

    // x2 for my 8 rows (rows ri*64 + ty*4 + i)
    float x2v[2][4];
    #pragma unroll
    for (int ri = 0; ri < 2; ++ri)
        #pragma unroll
        for (int i = 0; i < 4; ++i)
            x2v[ri][i] = x2 ? x2[rowBase + ri * 64 + ty * 4 + i] : 0.0f;

    float bestV[2][4];
    int   bestI[2][4];
    #pragma unroll
    for (int ri = 0; ri < 2; ++ri)
        #pragma unroll
        for (int i = 0; i < 4; ++i) { bestV[ri][i] = 3.4e38f; bestI[ri][i] = 0; }

    // staging mapping: thread -> (row r0+32p, float4-col c4) of a 128x32 tile
    const int s_c4 = tid & 7;
    const int s_r0 = tid >> 3;

    #pragma unroll 1
    for (int kt = 0; kt < K_CL / BN; ++kt) {
        const int k0 = kt * BN;
        float acc[2][4][2][4];
        #pragma unroll
        for (int ri = 0; ri < 2; ++ri)
            for (int i = 0; i < 4; ++i)
                for (int cj = 0; cj < 2; ++cj)
                    for (int j = 0; j < 4; ++j) acc[ri][i][cj][j] = 0.0f;

        #pragma unroll 1
        for (int dt = 0; dt < D_DIM / BK; ++dt) {
            const int d0 = dt * BK;
            __syncthreads();   // previous tile's reads done before overwrite
            // stage X[128][32] (transpose to d-major, swizzled)
            #pragma unroll
            for (int p = 0; p < 4; ++p) {
                int r = s_r0 + p * 32;
                float4 v = *(const float4*)&X[(size_t)(rowBase + r) * D_DIM + d0 + s_c4 * 4];
                #pragma unroll
                for (int j = 0; j < 4; ++j) {
                    int d = s_c4 * 4 + j;
                    Xs[d * BM + ((r + 4 * d) & 127)] = ((const float*)&v)[j];
                }
            }
            // stage C[128][32]
            #pragma unroll
            for (int p = 0; p < 4; ++p) {
                int r = s_r0 + p * 32;
                float4 v = *(const float4*)&C[(size_t)(k0 + r) * D_DIM + d0 + s_c4 * 4];
                #pragma unroll
                for (int j = 0; j < 4; ++j) {
                    int d = s_c4 * 4 + j;
                    Cs[d * BN + ((r + 4 * d) & 127)] = ((const float*)&v)[j];
                }
            }
            __syncthreads();

            #pragma unroll 4
            for (int d = 0; d < BK; ++d) {
                float4 a0 = *(const float4*)&Xs[d * BM + ((ty * 4      + 4 * d) & 127)];
                float4 a1 = *(const float4*)&Xs[d * BM + ((64 + ty * 4 + 4 * d) & 127)];
                float4 b0 = *(const float4*)&Cs[d * BN + ((tx * 4      + 4 * d) & 127)];
                float4 b1 = *(const float4*)&Cs[d * BN + ((64 + tx * 4 + 4 * d) & 127)];
                float a[2][4] = {{a0.x, a0.y, a0.z, a0.w}, {a1.x, a1.y, a1.z, a1.w}};
                float b[2][4] = {{b0.x, b0.y, b0.z, b0.w}, {b1.x, b1.y, b1.z, b1.w}};
                #pragma unroll
                for (int ri = 0; ri < 2; ++ri)
                    for (int i = 0; i < 4; ++i)
                        for (int cj = 0; cj < 2; ++cj)
                            for (int j = 0; j < 4; ++j)
                                acc[ri][i][cj][j] =
                                    fmaf(a[ri][i], b[cj][j], acc[ri][i][cj][j]);
            }
        }

        // fused argmin epilogue for this col tile.
        // cols ascend within thread (cj outer, j inner) + strict '<'
        // => first-occurrence tie rule within this thread's column set.
        #pragma unroll
        for (int cj = 0; cj < 2; ++cj)
            #pragma unroll
            for (int j = 0; j < 4; ++j) {
                int col = k0 + cj * 64 + tx * 4 + j;
                float cv = c2[col];
                #pragma unroll
                for (int ri = 0; ri < 2; ++ri)
                    #pragma unroll
                    for (int i = 0; i < 4; ++i) {
                        float v = x2v[ri][i] + cv - 2.0f * acc[ri][i][cj][j];
                        if (v < bestV[ri][i]) { bestV[ri][i] = v; bestI[ri][i] = col; }
                    }
            }
    }

    // cross-thread (tx) reduction: 16 candidates per row, lexicographic
    // (val, idx) min == global first-occurrence argmin.
    __syncthreads();
    float* rv = smem;                     // [128][16]
    int*   rx = (int*)(smem + 2048);      // [128][16]
    #pragma unroll
    for (int ri = 0; ri < 2; ++ri)
        #pragma unroll
        for (int i = 0; i < 4; ++i) {
            int r = ri * 64 + ty * 4 + i;
            rv[r * 16 + tx] = bestV[ri][i];
            rx[r * 16 + tx] = bestI[ri][i];
        }
    __syncthreads();
    if (tid < BM) {
        int r = tid;
        float bv = rv[r * 16];
        int   bi = rx[r * 16];
        #pragma unroll
        for (int t = 1; t < 16; ++t) {
            float v  = rv[r * 16 + t];
            int   ix = rx[r * 16 + t];
            if (v < bv || (v == bv && ix < bi)) { bv = v; bi = ix; }
        }
        out[rowBase + r] = bi;
    }
}

extern "C" void kernel_launch(void* const* d_in, const int* in_sizes, int n_in,
                              void* d_out, int out_size, void* d_ws, size_t ws_size,
                              hipStream_t stream) {
    const float* X = (const float*)d_in[0];   // [N, D]
    const float* C = (const float*)d_in[1];   // [K, D]
    int* out = (int*)d_out;

    float* ws = (float*)d_ws;
    float* x2 = nullptr;
    float* c2 = nullptr;
    size_t need_full = (size_t)(N_PTS + K_CL) * sizeof(float);
    if (ws_size >= need_full) { x2 = ws; c2 = ws + N_PTS; }
    else { c2 = ws; }   // argmin is invariant to the +x2 term; c2 needs 8 KB

    if (x2) {
        // N waves, 4 waves/block -> 32768 blocks
        row_norms_kernel<<<(N_PTS * 64) / 256, 256, 0, stream>>>(X, x2, N_PTS);
    }
    row_norms_kernel<<<(K_CL * 64) / 256, 256, 0, stream>>>(C, c2, K_CL);

    kmeans_argmin_kernel<<<N_PTS / BM, 256, 0, stream>>>(X, C, x2, c2, out);
}

// Round 2
// 1347.555 us; speedup vs baseline: 3.1814x; 3.1814x over previous
//
#include <hip/hip_runtime.h>

// K-means assignment via split-fp16 MFMA GEMM + fused argmin.
// d2 = x2 + c2 - 2*x.cT ; x = hi+lo (fp16 each), dot = hh + hl + lh on
// mfma_f32_16x16x32_f16 (fp32 accum). Error ~1e-6 < fp32 sum-order noise.
// N=131072, K=2048, D=512.

#define N_PTS 131072
#define K_CL  2048
#define D_DIM 512
#define BM 128
#define BN 128
#define BK 32

typedef _Float16 half8  __attribute__((ext_vector_type(8)));
typedef _Float16 half4v __attribute__((ext_vector_type(4)));
typedef float    floatx4 __attribute__((ext_vector_type(4)));

// async global->LDS, 16B per lane; LDS dest = wave-uniform base + lane*16
#define GLL(g, l) __builtin_amdgcn_global_load_lds( \
    (__attribute__((address_space(1))) void*)(g),   \
    (__attribute__((address_space(3))) void*)(l), 16, 0, 0)

// ---- c2 norms: one wave per row (identical numerics to round-1 pass) ----
__global__ void row_norms_kernel(const float* __restrict__ A,
                                 float* __restrict__ out, int rows) {
    int gid  = blockIdx.x * blockDim.x + threadIdx.x;
    int wave = gid >> 6;
    int lane = gid & 63;
    if (wave >= rows) return;
    const float4* a = (const float4*)(A + (size_t)wave * D_DIM);
    float4 p = a[lane];
    float4 q = a[lane + 64];
    float s = p.x*p.x + p.y*p.y + p.z*p.z + p.w*p.w
            + q.x*q.x + q.y*q.y + q.z*q.z + q.w*q.w;
    #pragma unroll
    for (int off = 32; off > 0; off >>= 1) s += __shfl_down(s, off, 64);
    if (lane == 0) out[wave] = s;
}

// ---- fp32 -> (hi,lo) fp16 planes ----
__global__ void conv_f16x2_kernel(const float* __restrict__ src,
                                  _Float16* __restrict__ hi,
                                  _Float16* __restrict__ lo, int n4) {
    int i = blockIdx.x * blockDim.x + threadIdx.x;
    if (i >= n4) return;
    float4 v = ((const float4*)src)[i];
    half4v h, l;
    h.x = (_Float16)v.x; h.y = (_Float16)v.y;
    h.z = (_Float16)v.z; h.w = (_Float16)v.w;
    l.x = (_Float16)(v.x - (float)h.x);
    l.y = (_Float16)(v.y - (float)h.y);
    l.z = (_Float16)(v.z - (float)h.z);
    l.w = (_Float16)(v.w - (float)h.w);
    *(half4v*)(hi + (size_t)i * 4) = h;
    *(half4v*)(lo + (size_t)i * 4) = l;
}

// ---- main: 128x128 block over all K, split-fp16 MFMA, fused argmin ----
// XPRE/CPRE: operand pre-converted in ws (stage via global_load_lds) vs
// fp32 load + convert + ds_write on the fly.
template<bool XPRE, bool CPRE>
__global__ __launch_bounds__(256, 3)
void kmeans_mfma(const float* __restrict__ X, const float* __restrict__ C,
                 const _Float16* __restrict__ Xhi, const _Float16* __restrict__ Xlo,
                 const _Float16* __restrict__ Chi, const _Float16* __restrict__ Clo,
                 const float* __restrict__ c2g, int* __restrict__ out) {
    // unpadded [row][BK] f16 tiles (64B rows) - required by global_load_lds
    __shared__ __align__(16) _Float16 sXh[BM * BK], sXl[BM * BK];
    __shared__ __align__(16) _Float16 sCh[BN * BK], sCl[BN * BK];
    __shared__ float c2s[K_CL];      // 8 KB
    __shared__ float x2s[BM];

    const int tid  = threadIdx.x;
    const int lane = tid & 63;
    const int w    = tid >> 6;       // wave id 0..3
    const int wti  = w >> 1;         // row half
    const int wtj  = w & 1;          // col half
    const int q    = lane >> 4;      // quad
    const int m16  = lane & 15;
    const int rowBase = blockIdx.x * BM;

    // c2 into LDS
    if (CPRE) {
        for (int i = tid; i < K_CL / 4; i += 256)
            ((float4*)c2s)[i] = ((const float4*)c2g)[i];
    } else {
        for (int k = tid; k < K_CL; k += 256) {
            const float4* cp = (const float4*)(C + (size_t)k * D_DIM);
            float s0 = 0.f, s1 = 0.f;
            for (int j = 0; j < D_DIM / 4; j += 2) {
                float4 a = cp[j], b = cp[j + 1];
                s0 += a.x*a.x + a.y*a.y + a.z*a.z + a.w*a.w;
                s1 += b.x*b.x + b.y*b.y + b.z*b.z + b.w*b.w;
            }
            c2s[k] = s0 + s1;
        }
    }
    // x2 into LDS (2 threads per row; partials staged in sXh scratch)
    {
        int r = tid & 127, h = tid >> 7;
        const float4* xp = (const float4*)(X + (size_t)(rowBase + r) * D_DIM + h * 256);
        float s0 = 0.f, s1 = 0.f;
        for (int j = 0; j < 64; j += 2) {
            float4 a = xp[j], b = xp[j + 1];
            s0 += a.x*a.x + a.y*a.y + a.z*a.z + a.w*a.w;
            s1 += b.x*b.x + b.y*b.y + b.z*b.z + b.w*b.w;
        }
        ((float*)sXh)[tid] = s0 + s1;
    }
    __syncthreads();
    if (tid < BM) x2s[tid] = ((float*)sXh)[tid] + ((float*)sXh)[tid + 128];

    float bestV[4][4];
    int   bestI[4][4];
    #pragma unroll
    for (int ti = 0; ti < 4; ++ti)
        #pragma unroll
        for (int r = 0; r < 4; ++r) { bestV[ti][r] = 3.4e38f; bestI[ti][r] = 0; }

    // on-the-fly staging mapping
    const int s_c4 = tid & 7;    // float4-col within BK
    const int s_r0 = tid >> 3;   // row 0..31

    #pragma unroll 1
    for (int kt = 0; kt < K_CL / BN; ++kt) {
        const int k0 = kt * BN;
        floatx4 acc[4][4];
        #pragma unroll
        for (int ti = 0; ti < 4; ++ti)
            #pragma unroll
            for (int tj = 0; tj < 4; ++tj) acc[ti][tj] = (floatx4){0.f, 0.f, 0.f, 0.f};

        #pragma unroll 1
        for (int dt = 0; dt < D_DIM / BK; ++dt) {
            const int d0 = dt * BK;
            __syncthreads();   // tile reads of previous iter done
            if (XPRE) {
                #pragma unroll
                for (int s = 0; s < 2; ++s) {
                    int c = w * 2 + s;                   // chunk: 16 LDS rows
                    int r = c * 16 + (lane >> 2);
                    size_t go = (size_t)(rowBase + r) * D_DIM + d0 + (lane & 3) * 8;
                    GLL(Xhi + go, &sXh[c * 512]);
                    GLL(Xlo + go, &sXl[c * 512]);
                }
            } else {
                #pragma unroll
                for (int p = 0; p < 4; ++p) {
                    int r = s_r0 + p * 32;
                    float4 v = *(const float4*)&X[(size_t)(rowBase + r) * D_DIM + d0 + s_c4 * 4];
                    half4v h, l;
                    h.x = (_Float16)v.x; h.y = (_Float16)v.y;
                    h.z = (_Float16)v.z; h.w = (_Float16)v.w;
                    l.x = (_Float16)(v.x - (float)h.x);
                    l.y = (_Float16)(v.y - (float)h.y);
                    l.z = (_Float16)(v.z - (float)h.z);
                    l.w = (_Float16)(v.w - (float)h.w);
                    *(half4v*)&sXh[r * BK + s_c4 * 4] = h;
                    *(half4v*)&sXl[r * BK + s_c4 * 4] = l;
                }
            }
            if (CPRE) {
                #pragma unroll
                for (int s = 0; s < 2; ++s) {
                    int c = w * 2 + s;
                    int r = c * 16 + (lane >> 2);
                    size_t go = (size_t)(k0 + r) * D_DIM + d0 + (lane & 3) * 8;
                    GLL(Chi + go, &sCh[c * 512]);
                    GLL(Clo + go, &sCl[c * 512]);
                }
            } else {
                #pragma unroll
                for (int p = 0; p < 4; ++p) {
                    int r = s_r0 + p * 32;
                    float4 v = *(const float4*)&C[(size_t)(k0 + r) * D_DIM + d0 + s_c4 * 4];
                    half4v h, l;
                    h.x = (_Float16)v.x; h.y = (_Float16)v.y;
                    h.z = (_Float16)v.z; h.w = (_Float16)v.w;
                    l.x = (_Float16)(v.x - (float)h.x);
                    l.y = (_Float16)(v.y - (float)h.y);
                    l.z = (_Float16)(v.z - (float)h.z);
                    l.w = (_Float16)(v.w - (float)h.w);
                    *(half4v*)&sCh[r * BK + s_c4 * 4] = h;
                    *(half4v*)&sCl[r * BK + s_c4 * 4] = l;
                }
            }
            __syncthreads();   // drains vmcnt (global_load_lds) + lgkm

            // A fragments: A[m=lane&15][k=quad*8+j]
            half8 ah[4], al[4];
            #pragma unroll
            for (int ti = 0; ti < 4; ++ti) {
                int row = wti * 64 + ti * 16 + m16;
                ah[ti] = *(const half8*)&sXh[row * BK + q * 8];
                al[ti] = *(const half8*)&sXl[row * BK + q * 8];
            }
            #pragma unroll
            for (int tj = 0; tj < 4; ++tj) {
                int col = wtj * 64 + tj * 16 + m16;
                half8 bh = *(const half8*)&sCh[col * BK + q * 8];
                half8 bl = *(const half8*)&sCl[col * BK + q * 8];
                #pragma unroll
                for (int ti = 0; ti < 4; ++ti) {
                    floatx4 a = acc[ti][tj];
                    a = __builtin_amdgcn_mfma_f32_16x16x32_f16(ah[ti], bh, a, 0, 0, 0);
                    a = __builtin_amdgcn_mfma_f32_16x16x32_f16(ah[ti], bl, a, 0, 0, 0);
                    a = __builtin_amdgcn_mfma_f32_16x16x32_f16(al[ti], bh, a, 0, 0, 0);
                    acc[ti][tj] = a;
                }
            }
        }

        // fused argmin epilogue. D layout: col=lane&15, row=quad*4+reg.
        // cols ascend (kt, then tj) per (ti,reg) + strict '<'  => first-occurrence.
        #pragma unroll
        for (int tj = 0; tj < 4; ++tj) {
            int col = k0 + wtj * 64 + tj * 16 + m16;
            float cv = c2s[col];
            #pragma unroll
            for (int ti = 0; ti < 4; ++ti)
                #pragma unroll
                for (int r = 0; r < 4; ++r) {
                    float s = x2s[wti * 64 + ti * 16 + q * 4 + r] + cv;
                    float v = s - 2.0f * acc[ti][tj][r];
                    if (v < bestV[ti][r]) { bestV[ti][r] = v; bestI[ti][r] = col; }
                }
        }
    }

    // cross-lane reduce over the 16 lanes sharing each row (lexicographic)
    #pragma unroll
    for (int ti = 0; ti < 4; ++ti)
        #pragma unroll
        for (int r = 0; r < 4; ++r) {
            float v = bestV[ti][r]; int ix = bestI[ti][r];
            #pragma unroll
            for (int off = 1; off < 16; off <<= 1) {
                float ov = __shfl_xor(v, off, 64);
                int   oi = __shfl_xor(ix, off, 64);
                if (ov < v || (ov == v && oi < ix)) { v = ov; ix = oi; }
            }
            bestV[ti][r] = v; bestI[ti][r] = ix;
        }

    __syncthreads();                   // tiles no longer needed; reuse as scratch
    float* rv  = (float*)sXh;          // [128][2]
    int*   rix = (int*)sCh;            // [128][2]
    if (m16 == 0) {
        #pragma unroll
        for (int ti = 0; ti < 4; ++ti)
            #pragma unroll
            for (int r = 0; r < 4; ++r) {
                int rloc = wti * 64 + ti * 16 + q * 4 + r;
                rv[rloc * 2 + wtj]  = bestV[ti][r];
                rix[rloc * 2 + wtj] = bestI[ti][r];
            }
    }
    __syncthreads();
    if (tid < BM) {
        float v0 = rv[tid * 2], v1 = rv[tid * 2 + 1];
        int   i0 = rix[tid * 2], i1 = rix[tid * 2 + 1];
        out[rowBase + tid] = (v1 < v0 || (v1 == v0 && i1 < i0)) ? i1 : i0;
    }
}

extern "C" void kernel_launch(void* const* d_in, const int* in_sizes, int n_in,
                              void* d_out, int out_size, void* d_ws, size_t ws_size,
                              hipStream_t stream) {
    const float* X = (const float*)d_in[0];   // [N, D]
    const float* C = (const float*)d_in[1];   // [K, D]
    int* out = (int*)d_out;

    char* ws = (char*)d_ws;
    const size_t c2_off  = 0;
    const size_t chi_off = (size_t)K_CL * 4;                       // 8 KB
    const size_t clo_off = chi_off + (size_t)K_CL * D_DIM * 2;     // +2 MB
    const size_t xhi_off = clo_off + (size_t)K_CL * D_DIM * 2;     // +2 MB
    const size_t xlo_off = xhi_off + (size_t)N_PTS * D_DIM * 2;    // +128 MB
    const size_t need_C    = xhi_off;                              // ~4.2 MB
    const size_t need_full = xlo_off + (size_t)N_PTS * D_DIM * 2;  // ~272.6 MB

    if (ws_size >= need_full) {
        float*    c2  = (float*)(ws + c2_off);
        _Float16* Chi = (_Float16*)(ws + chi_off);
        _Float16* Clo = (_Float16*)(ws + clo_off);
        _Float16* Xhi = (_Float16*)(ws + xhi_off);
        _Float16* Xlo = (_Float16*)(ws + xlo_off);
        row_norms_kernel<<<(K_CL * 64) / 256, 256, 0, stream>>>(C, c2, K_CL);
        conv_f16x2_kernel<<<(K_CL * D_DIM / 4) / 256, 256, 0, stream>>>(
            C, Chi, Clo, K_CL * D_DIM / 4);
        conv_f16x2_kernel<<<(N_PTS * D_DIM / 4 + 255) / 256, 256, 0, stream>>>(
            X, Xhi, Xlo, N_PTS * D_DIM / 4);
        kmeans_mfma<true, true><<<N_PTS / BM, 256, 0, stream>>>(
            X, C, Xhi, Xlo, Chi, Clo, c2, out);
    } else if (ws_size >= need_C) {
        float*    c2  = (float*)(ws + c2_off);
        _Float16* Chi = (_Float16*)(ws + chi_off);
        _Float16* Clo = (_Float16*)(ws + clo_off);
        row_norms_kernel<<<(K_CL * 64) / 256, 256, 0, stream>>>(C, c2, K_CL);
        conv_f16x2_kernel<<<(K_CL * D_DIM / 4) / 256, 256, 0, stream>>>(
            C, Chi, Clo, K_CL * D_DIM / 4);
        kmeans_mfma<false, true><<<N_PTS / BM, 256, 0, stream>>>(
            X, C, nullptr, nullptr, Chi, Clo, c2, out);
    } else {
        kmeans_mfma<false, false><<<N_PTS / BM, 256, 0, stream>>>(
            X, C, nullptr, nullptr, nullptr, nullptr, nullptr, out);
    }
}